// Round 7
// baseline (12184.601 us; speedup 1.0000x reference)
//
#include <hip/hip_runtime.h>
#include <cstdint>

#define DEV __device__ __forceinline__

typedef unsigned short ushort8 __attribute__((ext_vector_type(8)));
typedef unsigned int uint32;

#if __has_builtin(__builtin_amdgcn_rcpf)
DEV float rcp_fast(float x) { return __builtin_amdgcn_rcpf(x); }
#else
DEV float rcp_fast(float x) { return 1.f / x; }
#endif
#if __has_builtin(__builtin_amdgcn_exp2f)
DEV float exp2_fast(float x) { return __builtin_amdgcn_exp2f(x); }
#else
DEV float exp2_fast(float x) { return exp2f(x); }
#endif

#define SCALE2LOG2E 2.8853900817779268f  // 2*log2(e)
#define LOG2E 1.4426950408889634f

// tanh(x) = 1 - 2/(2^(x*SCALE2LOG2E)+1): safe at +/-inf.
DEV float tanh_fast(float x) {
  float z = exp2_fast(x * SCALE2LOG2E);
  return 1.f - 2.f * rcp_fast(z + 1.f);
}
DEV float sigmoid_fast(float x) {
  return rcp_fast(1.f + exp2_fast(-LOG2E * x));
}

// bf16 helpers (RTN pack; unpack via bit shift).
DEV unsigned short f2bf(float f) {
  uint32 u = __float_as_uint(f);
  u += 0x7FFFu + ((u >> 16) & 1u);
  return (unsigned short)(u >> 16);
}
DEV float bf2f(unsigned short s) { return __uint_as_float(((uint32)s) << 16); }
DEV float bf2f_lo(uint32 u) { return __uint_as_float(u << 16); }
DEV float bf2f_hi(uint32 u) { return __uint_as_float(u & 0xFFFF0000u); }

// padded s layout: s[m] at (m>>5)*34 + ((m>>1)&15)*2 + (m&1)
DEV int spad_idx(int m) {
  return (m >> 5) * 34 + ((m >> 1) & 15) * 2 + (m & 1);
}

// ------- prep: decoder cell weights -> bf16 pairs, [g][l][m][n2] -----------
__global__ __launch_bounds__(256) void k_prep(const float* __restrict__ RHw,
                                              const float* __restrict__ RTw,
                                              uint32* __restrict__ out) {
  int i = blockIdx.x * 256 + threadIdx.x;
  if (i >= 49152) return;
  int g = i / 24576, rem = i % 24576;       // rem = (l*128+m)*64 + n2
  int l = rem / 8192, rem2 = rem & 8191;
  int m = rem2 >> 6, n2 = rem2 & 63;
  const float* W = g ? RTw : RHw;
  float w0 = W[(size_t)(l * 128 + 2 * n2) * 128 + m];
  float w1 = W[(size_t)(l * 128 + 2 * n2 + 1) * 128 + m];
  out[i] = (uint32)f2bf(w0) | ((uint32)f2bf(w1) << 16);
}

// ---------------- conv0: [B,T,16] -> [B,T,64], k=5 pad=2, +bias, ReLU ------
__global__ __launch_bounds__(256) void k_conv0(
    const float* __restrict__ x, const float* __restrict__ w,
    const float* __restrict__ bias, float* __restrict__ out) {
  __shared__ float wl[16 * 5 * 64];
  __shared__ float xl[68 * 16];
  const int blk = blockIdx.x;
  const int b = blk >> 2, tt = blk & 3;
  const int tid = threadIdx.x;
  for (int i = tid; i < 5120; i += 256) {
    int o = i / 80, rem = i % 80, ii = rem / 5, kk = rem % 5;
    wl[(ii * 5 + kk) * 64 + o] = w[i];
  }
  const int t0 = tt * 64;
  for (int i = tid; i < 68 * 16; i += 256) {
    int row = i >> 4, c = i & 15;
    int t = t0 - 2 + row;
    xl[i] = (t >= 0 && t < 256) ? x[((b << 8) + t) * 16 + c] : 0.f;
  }
  __syncthreads();
  const int o = tid & 63, tr = tid >> 6;
  for (int j = 0; j < 16; ++j) {
    int tl = tr * 16 + j;
    float acc = bias[o];
#pragma unroll
    for (int kk = 0; kk < 5; ++kk)
#pragma unroll
      for (int ii = 0; ii < 16; ++ii)
        acc += xl[(tl + kk) * 16 + ii] * wl[(ii * 5 + kk) * 64 + o];
    out[((b << 8) + t0 + tl) * 64 + o] = fmaxf(acc, 0.f);
  }
}

// ---------------- conv1: [B,T,64] -> [B,T,64], k=5 pad=2, +bias, ReLU ------
__global__ __launch_bounds__(256) void k_conv1(
    const float* __restrict__ in0, const float* __restrict__ w,
    const float* __restrict__ bias, float* __restrict__ out) {
  __shared__ float wl[64 * 5 * 64];  // 80 KB
  __shared__ float xl[68 * 64];      // 17 KB
  const int blk = blockIdx.x;
  const int b = blk >> 2, tt = blk & 3;
  const int tid = threadIdx.x;
  for (int i = tid; i < 64 * 5 * 64; i += 256) {
    int o = i / 320, rem = i % 320, ii = rem / 5, kk = rem % 5;
    wl[(ii * 5 + kk) * 64 + o] = w[i];
  }
  const int t0 = tt * 64;
  for (int i = tid; i < 68 * 64; i += 256) {
    int row = i >> 6, c = i & 63;
    int t = t0 - 2 + row;
    xl[i] = (t >= 0 && t < 256) ? in0[((b << 8) + t) * 64 + c] : 0.f;
  }
  __syncthreads();
  const int o = tid & 63, tr = tid >> 6;
  for (int j = 0; j < 16; ++j) {
    int tl = tr * 16 + j;
    float acc = bias[o];
    for (int kk = 0; kk < 5; ++kk) {
#pragma unroll 16
      for (int ii = 0; ii < 64; ++ii)
        acc += xl[(tl + kk) * 64 + ii] * wl[(ii * 5 + kk) * 64 + o];
    }
    out[((b << 8) + t0 + tl) * 64 + o] = fmaxf(acc, 0.f);
  }
}

// --------- c2e (+bias) fused with encoder input projections x@WH, x@WT -----
__global__ __launch_bounds__(256) void k_c2e_proj(
    const float* __restrict__ in1, const float* __restrict__ cw,
    const float* __restrict__ cb, const float* __restrict__ WH,
    const float* __restrict__ WT, float* __restrict__ xph,
    float* __restrict__ xpt) {
  __shared__ float xin[64 * 64];
  __shared__ float w1[64 * 64];
  __shared__ float xe[64 * 64];
  __shared__ float wh[64 * 128];
  __shared__ float wt[64 * 128];
  const int blk = blockIdx.x;
  const int b = blk >> 2, tt = blk & 3;
  const int tid = threadIdx.x;
  for (int i = tid; i < 4096; i += 256) {
    xin[i] = in1[(size_t)(((b << 8) + tt * 64)) * 64 + i];
    w1[i] = cw[i];
  }
  for (int i = tid; i < 8192; i += 256) {
    wh[i] = WH[i];
    wt[i] = WT[i];
  }
  __syncthreads();
  {
    const int o = tid & 63, tr = tid >> 6;
    for (int j = 0; j < 16; ++j) {
      int tl = tr * 16 + j;
      float acc = cb[o];
#pragma unroll 16
      for (int k = 0; k < 64; ++k) acc += xin[tl * 64 + k] * w1[k * 64 + o];
      xe[tl * 64 + o] = acc;
    }
  }
  __syncthreads();
  {
    const int m = tid & 127, hf = tid >> 7;
    for (int j = 0; j < 32; ++j) {
      int tl = hf * 32 + j;
      float a0 = 0.f, a1 = 0.f;
#pragma unroll 16
      for (int k = 0; k < 64; ++k) {
        float xv = xe[tl * 64 + k];
        a0 += xv * wh[k * 128 + m];
        a1 += xv * wt[k * 128 + m];
      }
      size_t oidx = (size_t)((b << 8) + tt * 64 + tl) * 128 + m;
      xph[oidx] = a0;
      xpt[oidx] = a1;
    }
  }
}

// ---------------- encoder RHN: one block per batch row ---------------------
__global__ __launch_bounds__(512, 2) void k_encoder(
    const float* __restrict__ xph, const float* __restrict__ xpt,
    const float* __restrict__ RHw, const float* __restrict__ RHb,
    const float* __restrict__ RTw, const float* __restrict__ RTb,
    unsigned short* __restrict__ h_bf) {
  const int b = blockIdx.x;
  const int tid = threadIdx.x;
  const int g = tid >> 8;
  const int m = (tid >> 1) & 127;
  const int hf = tid & 1;
  const float* W = g ? RTw : RHw;
  const float* Bb = g ? RTb : RHb;
  const float* XP = g ? xpt : xph;
  float wreg[3][64];
#pragma unroll
  for (int l = 0; l < 3; ++l)
#pragma unroll
    for (int j = 0; j < 64; ++j)
      wreg[l][j] = W[(size_t)(l * 128 + hf * 64 + j) * 128 + m];
  float bias[3];
#pragma unroll
  for (int l = 0; l < 3; ++l) bias[l] = Bb[l * 128 + m];

  __shared__ float s_lds[128];
  __shared__ float hg[128];
  __shared__ float tg[128];
  if (tid < 128) s_lds[tid] = 0.f;
  __syncthreads();

  for (int t = 0; t < 256; ++t) {
    const float xp = XP[(size_t)((b << 8) + t) * 128 + m];
#pragma unroll
    for (int l = 0; l < 3; ++l) {
      float acc = (hf == 0) ? (bias[l] + (l == 0 ? xp : 0.f)) : 0.f;
      const float* sp = s_lds + hf * 64;
#pragma unroll
      for (int j = 0; j < 64; ++j) acc += sp[j] * wreg[l][j];
      float tot = acc + __shfl_xor(acc, 1);
      if (hf == 0) {
        if (g == 0) hg[m] = tanh_fast(tot);
        else        tg[m] = sigmoid_fast(tot);
      }
      __syncthreads();
      if (tid < 128) {
        float tv = tg[tid];
        float sn = hg[tid] * tv + (1.f - tv) * s_lds[tid];
        s_lds[tid] = sn;
        h_bf[((size_t)(b * 3 + l) * 256 + t) * 128 + tid] = f2bf(sn);
      }
      __syncthreads();
    }
  }
}

// Uh2[b][r][t][m] = bf16( SCALE2LOG2E * (h.Uk_w[r] + Uk_b[r]) )  (prescaled)
__global__ __launch_bounds__(256, 2) void k_uh(
    const unsigned short* __restrict__ h_bf, const float* __restrict__ Uk_w,
    const float* __restrict__ Uk_b, unsigned short* __restrict__ Uh_bf) {
  __shared__ float wl[128 * 128];  // 64 KB
  __shared__ float hl[32 * 128];   // 16 KB
  const int blk = blockIdx.x;      // 768 = 256 b x 3 r
  const int b = blk / 3, r = blk % 3;
  const int tid = threadIdx.x;
  for (int i = tid; i < 16384; i += 256) wl[i] = Uk_w[(size_t)r * 16384 + i];
  const int m = tid & 127, tr = tid >> 7;
  const float ub = Uk_b[r * 128 + m];
  for (int tt = 0; tt < 8; ++tt) {
    const size_t hbase = ((size_t)(b * 3 + r) * 256 + tt * 32) * 128;
    __syncthreads();  // previous tile's compute done before hl overwrite
    const ushort8* hv = (const ushort8*)(h_bf + hbase);
    for (int i = tid; i < 512; i += 256) {
      ushort8 u = hv[i];
#pragma unroll
      for (int j = 0; j < 8; ++j) hl[i * 8 + j] = bf2f(u[j]);
    }
    __syncthreads();
    for (int j = 0; j < 16; ++j) {
      int tl = tr * 16 + j;
      float acc = ub;
#pragma unroll 16
      for (int n = 0; n < 128; ++n) acc += hl[tl * 128 + n] * wl[n * 128 + m];
      Uh_bf[hbase + (size_t)tl * 128 + m] = f2bf(acc * SCALE2LOG2E);
    }
  }
}

// ------ hv[b][r][t] = h[b][r][t][:].Vt_w[r];  hv2 likewise with V_w --------
__global__ __launch_bounds__(768) void k_hv(
    const unsigned short* __restrict__ h_bf, const float* __restrict__ Vt_w,
    const float* __restrict__ V_w, float* __restrict__ hv,
    float* __restrict__ hv2) {
  __shared__ float vt[384], vw[384];
  const int b = blockIdx.x, tid = threadIdx.x;
  if (tid < 384) {
    vt[tid] = Vt_w[tid];
    vw[tid] = V_w[tid];
  }
  __syncthreads();
  const int r = tid >> 8;
  const uint2* hp = (const uint2*)(h_bf + ((size_t)b * 768 + tid) * 128);
  const float* vtp = vt + r * 128;
  const float* vwp = vw + r * 128;
  float a1 = 0.f, a2 = 0.f;
#pragma unroll 8
  for (int q = 0; q < 32; ++q) {
    uint2 u = hp[q];
    int m = q * 4;
    float h0 = bf2f_lo(u.x), h1 = bf2f_hi(u.x);
    float h2 = bf2f_lo(u.y), h3 = bf2f_hi(u.y);
    a1 += vtp[m] * h0 + vtp[m + 1] * h1 + vtp[m + 2] * h2 + vtp[m + 3] * h3;
    a2 += vwp[m] * h0 + vwp[m + 1] * h1 + vwp[m + 2] * h2 + vwp[m + 3] * h3;
  }
  hv[(size_t)b * 768 + tid] = a1;
  hv2[(size_t)b * 768 + tid] = a2;
}

// ---------------- attentive RHN decoder: one block per batch row -----------
// 1024 threads. Attention role: (t = tid>>2, q4 = tid&3 m-quarter); 48
// persistent prescaled-Uh dwords per thread (round-5-proven resident size).
// e-phase: w = 1/(exp2(Uh2+Ts2)+1), e = svk + sum(-2vk*w); p-reduce via
// segregated butterfly (xor 4,8,16,32 keeps q4 classes apart). Cell: thread
// = (m, gate, chunk) lane-adjacent, combine by 3 shfl_xor, 1 barrier per
// micro-step, double-buffered padded s. 5 barriers/step.
__global__ __launch_bounds__(1024, 4) void k_decoder(
    const float* __restrict__ y, const unsigned short* __restrict__ Uh_bf,
    const float* __restrict__ hv_g, const float* __restrict__ hv2_g,
    const float* __restrict__ Tk_w, const float* __restrict__ vk_w,
    const float* __restrict__ vk_b, const float* __restrict__ Wt_w,
    const float* __restrict__ Vt_b, const float* __restrict__ WHd,
    const float* __restrict__ WTd, const uint32* __restrict__ cellw,
    const float* __restrict__ RHb, const float* __restrict__ RTb,
    const float* __restrict__ W_w, const float* __restrict__ W_b,
    const float* __restrict__ V_b, float* __restrict__ out) {
  const int b = blockIdx.x, tid = threadIdx.x;

  __shared__ uint32 tk_lds[24576];             // [r][j(64)][m(128)], 96 KiB
  __shared__ __align__(16) float4 tsvk4[3 * 4 * 17];  // [r][q4][17]: Ts2|-2vk
  __shared__ float s_pad[2][136];              // double-buffered padded s
  __shared__ float hv_lds[768], hv2_lds[768];
  __shared__ float bias_lds[1024];  // RHb[384] RTb[384] WHd[128] WTd[128]
  __shared__ float y_lds[256];
  __shared__ float redN[48], redD[48], redN2[48];  // [wave][r]
  __shared__ float svk_lds[3];

  // ---- one-time fills ----
  for (int i = tid; i < 24576; i += 1024) {
    int r = i >> 13, rem = i & 8191, j = rem >> 7, m = rem & 127;
    float g0 = Tk_w[(size_t)r * 16384 + (2 * j) * 128 + m] * SCALE2LOG2E;
    float g1 = Tk_w[(size_t)r * 16384 + (2 * j + 1) * 128 + m] * SCALE2LOG2E;
    tk_lds[i] = (uint32)f2bf(g0) | ((uint32)f2bf(g1) << 16);
  }
  if (tid < 192) {  // -2*vk into .z/.w
    int r = tid >> 6, rem = tid & 63, q4i = rem >> 4, j = rem & 15;
    int mb = q4i * 32 + 2 * j;
    tsvk4[(r * 4 + q4i) * 17 + j].z = -2.f * vk_w[r * 128 + mb];
    tsvk4[(r * 4 + q4i) * 17 + j].w = -2.f * vk_w[r * 128 + mb + 1];
  }
  if (tid < 3) {
    float sv = vk_b[tid];
    for (int m = 0; m < 128; ++m) sv += vk_w[tid * 128 + m];
    svk_lds[tid] = sv;
  }
  if (tid < 384) {
    bias_lds[tid] = RHb[tid];
    bias_lds[384 + tid] = RTb[tid];
  }
  if (tid < 128) {
    bias_lds[768 + tid] = WHd[tid];
    bias_lds[896 + tid] = WTd[tid];
  }
  if (tid < 272) ((float*)s_pad)[tid] = 0.f;
  if (tid < 256) y_lds[tid] = y[(b << 8) + tid];
  if (tid < 768) {
    hv_lds[tid] = hv_g[(size_t)b * 768 + tid];
    hv2_lds[tid] = hv2_g[(size_t)b * 768 + tid];
  }
  const float wt0 = Wt_w[0], vtb0 = Vt_b[0];

  // ---- persistent Uh (prescaled): 3 r x 16 dwords = 48 VGPR ----
  const int t_e4 = tid >> 2, q4 = tid & 3;
  uint32 ureg[3][16];
#pragma unroll
  for (int r = 0; r < 3; ++r) {
    const uint4* up = (const uint4*)(Uh_bf +
        ((size_t)(b * 3 + r) * 256 + t_e4) * 128 + q4 * 32);
#pragma unroll
    for (int q = 0; q < 4; ++q) {
      uint4 v = up[q];
      ureg[r][4 * q + 0] = v.x;
      ureg[r][4 * q + 1] = v.y;
      ureg[r][4 * q + 2] = v.z;
      ureg[r][4 * q + 3] = v.w;
    }
  }
  uint32 zr;
  asm volatile("s_mov_b32 %0, 0" : "=s"(zr));
#pragma unroll
  for (int r = 0; r < 3; ++r)
#pragma unroll
    for (int q = 0; q < 16; ++q) ureg[r][q] ^= zr;
  __syncthreads();

  const int lane = tid & 63, wv = tid >> 6;
  // Ts-phase role (tid < 768): (rT, m2, p2)
  const int rT = tid >> 8, m2 = (tid >> 1) & 127, p2 = tid & 1;
  // cell role: (mC, gC, chC) lane-adjacent
  const int mC = tid >> 3, sub = tid & 7, gC = sub >> 2, chC = sub & 3;
  const int sidx = spad_idx(mC);
  int spb = 0;

  for (int step = 0; step < 256; ++step) {
    // ---- (A) Ts2[r][m] = s @ Tk2[r]  (768 threads, pair-split n) ----
    if (tid < 768) {
      const uint32* tkp = tk_lds + rT * 8192 + m2;
      const float* sc = s_pad[spb];
      float acc = 0.f;
#pragma unroll 8
      for (int jj = 0; jj < 32; ++jj) {
        int pr = p2 * 32 + jj;
        uint32 w = tkp[pr * 128];
        float2 sv = *(const float2*)(sc + ((pr >> 4) * 17 + (pr & 15)) * 2);
        acc += sv.x * bf2f_lo(w) + sv.y * bf2f_hi(w);
      }
      float tot = acc + __shfl_xor(acc, 1);
      if (p2 == 0)
        ((float*)&tsvk4[(rT * 4 + (m2 >> 5)) * 17 + ((m2 & 31) >> 1)])[m2 & 1] = tot;
    }
    __syncthreads();  // (1)
    // ---- (B) e + p + segregated num/den reduce (Uh in regs) ----
    {
      float er[3];
#pragma unroll
      for (int r = 0; r < 3; ++r) {
        const float4* tv4 = tsvk4 + (r * 4 + q4) * 17;
        float acc0 = 0.f, acc1 = 0.f;
#pragma unroll
        for (int j = 0; j < 16; ++j) {
          uint32 w = ureg[r][j];
          float4 q = tv4[j];
          float z0 = exp2_fast(bf2f_lo(w) + q.x);
          float z1 = exp2_fast(bf2f_hi(w) + q.y);
          acc0 += q.z * rcp_fast(z0 + 1.f);
          acc1 += q.w * rcp_fast(z1 + 1.f);
        }
        float a = acc0 + acc1;
        a += __shfl_xor(a, 1);
        a += __shfl_xor(a, 2);
        er[r] = a + svk_lds[r];
      }
      // lane's quad-slot q4 owns r = q4 (q4==3 idles)
      float pn = 0.f, pd = 0.f, pn2 = 0.f;
      if (q4 < 3) {
        float p = exp2_fast(er[q4] * LOG2E);
        pd = p;
        pn = p * hv_lds[q4 * 256 + t_e4];
        if (step == 255) pn2 = p * hv2_lds[q4 * 256 + t_e4];
      }
#pragma unroll
      for (int off = 4; off < 64; off <<= 1) {  // keeps q4 classes separate
        pn += __shfl_xor(pn, off);
        pd += __shfl_xor(pd, off);
      }
      if (step == 255) {
#pragma unroll
        for (int off = 4; off < 64; off <<= 1) pn2 += __shfl_xor(pn2, off);
        if (lane < 3) redN2[wv * 3 + lane] = pn2;
      }
      if (lane < 3) {
        redN[wv * 3 + lane] = pn;
        redD[wv * 3 + lane] = pd;
      }
    }
    __syncthreads();  // (2)
    // ---- (C) ytil redundantly in all threads (broadcast LDS reads) ----
    float ytil = y_lds[step] * wt0 + vtb0;
#pragma unroll
    for (int r = 0; r < 3; ++r) {
      float ns = 0.f, ds = 0.f;
#pragma unroll
      for (int w = 0; w < 16; ++w) {
        ns += redN[w * 3 + r];
        ds += redD[w * 3 + r];
      }
      ytil += ns * rcp_fast(ds);
    }
    // ---- (D) cell: 3 micro-steps, 1 barrier each ----
#pragma unroll
    for (int l = 0; l < 3; ++l) {
      const float* sc = s_pad[spb];
      const float2* sp2 = (const float2*)sc + chC * 17;
      const uint4* wp = (const uint4*)(cellw + (((size_t)(gC * 3 + l)) << 13) +
                                       (mC << 6) + (chC << 4));
      uint4 wa = wp[0], wb4 = wp[1], wc = wp[2], wd = wp[3];
      float acc = 0.f;
#pragma unroll
      for (int j = 0; j < 4; ++j) {
        uint4 w4 = (j == 0) ? wa : (j == 1) ? wb4 : (j == 2) ? wc : wd;
        float2 sa = sp2[j * 4 + 0];
        acc += sa.x * bf2f_lo(w4.x) + sa.y * bf2f_hi(w4.x);
        float2 sb = sp2[j * 4 + 1];
        acc += sb.x * bf2f_lo(w4.y) + sb.y * bf2f_hi(w4.y);
        float2 sd = sp2[j * 4 + 2];
        acc += sd.x * bf2f_lo(w4.z) + sd.y * bf2f_hi(w4.z);
        float2 se = sp2[j * 4 + 3];
        acc += se.x * bf2f_lo(w4.w) + se.y * bf2f_hi(w4.w);
      }
      acc += __shfl_xor(acc, 1);
      acc += __shfl_xor(acc, 2);
      float other = __shfl_xor(acc, 4);
      float hsum = gC ? other : acc;
      float tsum = gC ? acc : other;
      float s_old = sc[sidx];
      float ha = hsum + bias_lds[l * 128 + mC];
      float ta = tsum + bias_lds[384 + l * 128 + mC];
      if (l == 0) {
        ha += ytil * bias_lds[768 + mC];
        ta += ytil * bias_lds[896 + mC];
      }
      float hvv = tanh_fast(ha);
      float tv = sigmoid_fast(ta);
      if (sub == 0) s_pad[spb ^ 1][sidx] = hvv * tv + (1.f - tv) * s_old;
      __syncthreads();  // (3/4/5)
      spb ^= 1;
    }
  }
  // ---- output head ----
  if (tid < 64) {
    const float* sc = s_pad[spb];
    float acc = sc[spad_idx(tid)] * W_w[tid] + sc[spad_idx(tid + 64)] * W_w[tid + 64];
#pragma unroll
    for (int off = 32; off; off >>= 1) acc += __shfl_xor(acc, off);
    if (tid == 0) {
      float o = acc + W_b[0] + V_b[0];
#pragma unroll
      for (int r = 0; r < 3; ++r) {
        float ns = 0.f, ds = 0.f;
#pragma unroll
        for (int w = 0; w < 16; ++w) {
          ns += redN2[w * 3 + r];
          ds += redD[w * 3 + r];
        }
        o += ns * rcp_fast(ds);
      }
      out[b] = o;
    }
  }
}

extern "C" void kernel_launch(void* const* d_in, const int* in_sizes, int n_in,
                              void* d_out, int out_size, void* d_ws,
                              size_t ws_size, hipStream_t stream) {
  (void)in_sizes; (void)n_in; (void)out_size; (void)ws_size;
  const float* x    = (const float*)d_in[0];
  const float* y    = (const float*)d_in[1];
  const float* c0w  = (const float*)d_in[2];
  const float* c0b  = (const float*)d_in[3];
  const float* c1w  = (const float*)d_in[4];
  const float* c1b  = (const float*)d_in[5];
  const float* c2ew = (const float*)d_in[6];
  const float* c2eb = (const float*)d_in[7];
  const float* eWH  = (const float*)d_in[8];
  const float* eWT  = (const float*)d_in[9];
  const float* eRHw = (const float*)d_in[10];
  const float* eRHb = (const float*)d_in[11];
  const float* eRTw = (const float*)d_in[12];
  const float* eRTb = (const float*)d_in[13];
  const float* dWH  = (const float*)d_in[14];
  const float* dWT  = (const float*)d_in[15];
  const float* dRHw = (const float*)d_in[16];
  const float* dRHb = (const float*)d_in[17];
  const float* dRTw = (const float*)d_in[18];
  const float* dRTb = (const float*)d_in[19];
  const float* Tk   = (const float*)d_in[20];
  const float* Ukw  = (const float*)d_in[21];
  const float* Ukb  = (const float*)d_in[22];
  const float* vkw  = (const float*)d_in[23];
  const float* vkb  = (const float*)d_in[24];
  const float* Wtw  = (const float*)d_in[25];
  const float* Vtw  = (const float*)d_in[26];
  const float* Vtb  = (const float*)d_in[27];
  const float* Ww   = (const float*)d_in[28];
  const float* Wb   = (const float*)d_in[29];
  const float* Vw   = (const float*)d_in[30];
  const float* Vb   = (const float*)d_in[31];
  float* out = (float*)d_out;
  float* ws = (float*)d_ws;

  // Workspace layout (float units), same as round 5.
  unsigned short* h_bf  = (unsigned short*)ws;
  unsigned short* Uh_bf = (unsigned short*)(ws + 12582912);
  float* xph = ws + 12582912;
  float* xpt = ws + 20971520;
  float* c0o = ws + 29360128;
  float* hv  = ws + 29360128;   // aliases c0o (dead by k_hv time)
  float* hv2 = ws + 30146560;
  float* c1o = ws + 33554432;
  uint32* cellw = (uint32*)(ws + 37748736);

  k_prep<<<192, 256, 0, stream>>>(dRHw, dRTw, cellw);
  k_conv0<<<1024, 256, 0, stream>>>(x, c0w, c0b, c0o);
  k_conv1<<<1024, 256, 0, stream>>>(c0o, c1w, c1b, c1o);
  k_c2e_proj<<<1024, 256, 0, stream>>>(c1o, c2ew, c2eb, eWH, eWT, xph, xpt);
  k_encoder<<<256, 512, 0, stream>>>(xph, xpt, eRHw, eRHb, eRTw, eRTb, h_bf);
  k_uh<<<768, 256, 0, stream>>>(h_bf, Ukw, Ukb, Uh_bf);
  k_hv<<<256, 768, 0, stream>>>(h_bf, Vtw, Vw, hv, hv2);
  k_decoder<<<256, 1024, 0, stream>>>(y, Uh_bf, hv, hv2, Tk, vkw, vkb, Wtw,
                                      Vtb, dWH, dWT, cellw, dRHb, dRTb,
                                      Ww, Wb, Vb, out);
}

// Round 8
// 4901.013 us; speedup vs baseline: 2.4861x; 2.4861x over previous
//
#include <hip/hip_runtime.h>
#include <cstdint>

#define DEV __device__ __forceinline__

typedef unsigned short ushort8 __attribute__((ext_vector_type(8)));
typedef unsigned int uint32;

#if __has_builtin(__builtin_amdgcn_rcpf)
DEV float rcp_fast(float x) { return __builtin_amdgcn_rcpf(x); }
#else
DEV float rcp_fast(float x) { return 1.f / x; }
#endif
#if __has_builtin(__builtin_amdgcn_exp2f)
DEV float exp2_fast(float x) { return __builtin_amdgcn_exp2f(x); }
#else
DEV float exp2_fast(float x) { return exp2f(x); }
#endif

#define SCALE2LOG2E 2.8853900817779268f  // 2*log2(e)
#define LOG2E 1.4426950408889634f

// tanh(x) = 1 - 2/(2^(x*SCALE2LOG2E)+1): safe at +/-inf.
DEV float tanh_fast(float x) {
  float z = exp2_fast(x * SCALE2LOG2E);
  return 1.f - 2.f * rcp_fast(z + 1.f);
}
DEV float sigmoid_fast(float x) {
  return rcp_fast(1.f + exp2_fast(-LOG2E * x));
}

// bf16 helpers (RTN pack; unpack via bit shift).
DEV unsigned short f2bf(float f) {
  uint32 u = __float_as_uint(f);
  u += 0x7FFFu + ((u >> 16) & 1u);
  return (unsigned short)(u >> 16);
}
DEV float bf2f(unsigned short s) { return __uint_as_float(((uint32)s) << 16); }
DEV float bf2f_lo(uint32 u) { return __uint_as_float(u << 16); }
DEV float bf2f_hi(uint32 u) { return __uint_as_float(u & 0xFFFF0000u); }

// ------- prep: decoder cell weights -> bf16 n-pair-packed dwords -----------
// out[g][l][n2][m] = pack(w[l][2*n2][m], w[l][2*n2+1][m]); g=0:RHw, g=1:RTw.
__global__ __launch_bounds__(256) void k_prep(const float* __restrict__ RHw,
                                              const float* __restrict__ RTw,
                                              uint32* __restrict__ out) {
  int i = blockIdx.x * 256 + threadIdx.x;
  if (i >= 49152) return;
  int g = i / 24576, rem = i % 24576;
  int l = rem / 8192, n2 = (rem >> 7) & 63, m = rem & 127;
  const float* W = g ? RTw : RHw;
  float w0 = W[(size_t)(l * 128 + 2 * n2) * 128 + m];
  float w1 = W[(size_t)(l * 128 + 2 * n2 + 1) * 128 + m];
  out[i] = (uint32)f2bf(w0) | ((uint32)f2bf(w1) << 16);
}

// ---------------- conv0: [B,T,16] -> [B,T,64], k=5 pad=2, +bias, ReLU ------
__global__ __launch_bounds__(256) void k_conv0(
    const float* __restrict__ x, const float* __restrict__ w,
    const float* __restrict__ bias, float* __restrict__ out) {
  __shared__ float wl[16 * 5 * 64];
  __shared__ float xl[68 * 16];
  const int blk = blockIdx.x;
  const int b = blk >> 2, tt = blk & 3;
  const int tid = threadIdx.x;
  for (int i = tid; i < 5120; i += 256) {
    int o = i / 80, rem = i % 80, ii = rem / 5, kk = rem % 5;
    wl[(ii * 5 + kk) * 64 + o] = w[i];
  }
  const int t0 = tt * 64;
  for (int i = tid; i < 68 * 16; i += 256) {
    int row = i >> 4, c = i & 15;
    int t = t0 - 2 + row;
    xl[i] = (t >= 0 && t < 256) ? x[((b << 8) + t) * 16 + c] : 0.f;
  }
  __syncthreads();
  const int o = tid & 63, tr = tid >> 6;
  for (int j = 0; j < 16; ++j) {
    int tl = tr * 16 + j;
    float acc = bias[o];
#pragma unroll
    for (int kk = 0; kk < 5; ++kk)
#pragma unroll
      for (int ii = 0; ii < 16; ++ii)
        acc += xl[(tl + kk) * 16 + ii] * wl[(ii * 5 + kk) * 64 + o];
    out[((b << 8) + t0 + tl) * 64 + o] = fmaxf(acc, 0.f);
  }
}

// ---------------- conv1: [B,T,64] -> [B,T,64], k=5 pad=2, +bias, ReLU ------
__global__ __launch_bounds__(256) void k_conv1(
    const float* __restrict__ in0, const float* __restrict__ w,
    const float* __restrict__ bias, float* __restrict__ out) {
  __shared__ float wl[64 * 5 * 64];  // 80 KB
  __shared__ float xl[68 * 64];      // 17 KB
  const int blk = blockIdx.x;
  const int b = blk >> 2, tt = blk & 3;
  const int tid = threadIdx.x;
  for (int i = tid; i < 64 * 5 * 64; i += 256) {
    int o = i / 320, rem = i % 320, ii = rem / 5, kk = rem % 5;
    wl[(ii * 5 + kk) * 64 + o] = w[i];
  }
  const int t0 = tt * 64;
  for (int i = tid; i < 68 * 64; i += 256) {
    int row = i >> 6, c = i & 63;
    int t = t0 - 2 + row;
    xl[i] = (t >= 0 && t < 256) ? in0[((b << 8) + t) * 64 + c] : 0.f;
  }
  __syncthreads();
  const int o = tid & 63, tr = tid >> 6;
  for (int j = 0; j < 16; ++j) {
    int tl = tr * 16 + j;
    float acc = bias[o];
    for (int kk = 0; kk < 5; ++kk) {
#pragma unroll 16
      for (int ii = 0; ii < 64; ++ii)
        acc += xl[(tl + kk) * 64 + ii] * wl[(ii * 5 + kk) * 64 + o];
    }
    out[((b << 8) + t0 + tl) * 64 + o] = fmaxf(acc, 0.f);
  }
}

// --------- c2e (+bias) fused with encoder input projections x@WH, x@WT -----
__global__ __launch_bounds__(256) void k_c2e_proj(
    const float* __restrict__ in1, const float* __restrict__ cw,
    const float* __restrict__ cb, const float* __restrict__ WH,
    const float* __restrict__ WT, float* __restrict__ xph,
    float* __restrict__ xpt) {
  __shared__ float xin[64 * 64];
  __shared__ float w1[64 * 64];
  __shared__ float xe[64 * 64];
  __shared__ float wh[64 * 128];
  __shared__ float wt[64 * 128];
  const int blk = blockIdx.x;
  const int b = blk >> 2, tt = blk & 3;
  const int tid = threadIdx.x;
  for (int i = tid; i < 4096; i += 256) {
    xin[i] = in1[(size_t)(((b << 8) + tt * 64)) * 64 + i];
    w1[i] = cw[i];
  }
  for (int i = tid; i < 8192; i += 256) {
    wh[i] = WH[i];
    wt[i] = WT[i];
  }
  __syncthreads();
  {
    const int o = tid & 63, tr = tid >> 6;
    for (int j = 0; j < 16; ++j) {
      int tl = tr * 16 + j;
      float acc = cb[o];
#pragma unroll 16
      for (int k = 0; k < 64; ++k) acc += xin[tl * 64 + k] * w1[k * 64 + o];
      xe[tl * 64 + o] = acc;
    }
  }
  __syncthreads();
  {
    const int m = tid & 127, hf = tid >> 7;
    for (int j = 0; j < 32; ++j) {
      int tl = hf * 32 + j;
      float a0 = 0.f, a1 = 0.f;
#pragma unroll 16
      for (int k = 0; k < 64; ++k) {
        float xv = xe[tl * 64 + k];
        a0 += xv * wh[k * 128 + m];
        a1 += xv * wt[k * 128 + m];
      }
      size_t oidx = (size_t)((b << 8) + tt * 64 + tl) * 128 + m;
      xph[oidx] = a0;
      xpt[oidx] = a1;
    }
  }
}

// ---------------- encoder RHN: one block per batch row ---------------------
__global__ __launch_bounds__(512, 2) void k_encoder(
    const float* __restrict__ xph, const float* __restrict__ xpt,
    const float* __restrict__ RHw, const float* __restrict__ RHb,
    const float* __restrict__ RTw, const float* __restrict__ RTb,
    unsigned short* __restrict__ h_bf) {
  const int b = blockIdx.x;
  const int tid = threadIdx.x;
  const int g = tid >> 8;
  const int m = (tid >> 1) & 127;
  const int hf = tid & 1;
  const float* W = g ? RTw : RHw;
  const float* Bb = g ? RTb : RHb;
  const float* XP = g ? xpt : xph;
  float wreg[3][64];
#pragma unroll
  for (int l = 0; l < 3; ++l)
#pragma unroll
    for (int j = 0; j < 64; ++j)
      wreg[l][j] = W[(size_t)(l * 128 + hf * 64 + j) * 128 + m];
  float bias[3];
#pragma unroll
  for (int l = 0; l < 3; ++l) bias[l] = Bb[l * 128 + m];

  __shared__ float s_lds[128];
  __shared__ float hg[128];
  __shared__ float tg[128];
  if (tid < 128) s_lds[tid] = 0.f;
  __syncthreads();

  for (int t = 0; t < 256; ++t) {
    const float xp = XP[(size_t)((b << 8) + t) * 128 + m];
#pragma unroll
    for (int l = 0; l < 3; ++l) {
      float acc = (hf == 0) ? (bias[l] + (l == 0 ? xp : 0.f)) : 0.f;
      const float* sp = s_lds + hf * 64;
#pragma unroll
      for (int j = 0; j < 64; ++j) acc += sp[j] * wreg[l][j];
      float tot = acc + __shfl_xor(acc, 1);
      if (hf == 0) {
        if (g == 0) hg[m] = tanh_fast(tot);
        else        tg[m] = sigmoid_fast(tot);
      }
      __syncthreads();
      if (tid < 128) {
        float tv = tg[tid];
        float sn = hg[tid] * tv + (1.f - tv) * s_lds[tid];
        s_lds[tid] = sn;
        h_bf[((size_t)(b * 3 + l) * 256 + t) * 128 + tid] = f2bf(sn);
      }
      __syncthreads();
    }
  }
}

// Uh2[b][r][t][m] = bf16( SCALE2LOG2E * (h.Uk_w[r] + Uk_b[r]) )  (prescaled)
__global__ __launch_bounds__(256, 2) void k_uh(
    const unsigned short* __restrict__ h_bf, const float* __restrict__ Uk_w,
    const float* __restrict__ Uk_b, unsigned short* __restrict__ Uh_bf) {
  __shared__ float wl[128 * 128];  // 64 KB
  __shared__ float hl[32 * 128];   // 16 KB
  const int blk = blockIdx.x;      // 768 = 256 b x 3 r
  const int b = blk / 3, r = blk % 3;
  const int tid = threadIdx.x;
  for (int i = tid; i < 16384; i += 256) wl[i] = Uk_w[(size_t)r * 16384 + i];
  const int m = tid & 127, tr = tid >> 7;
  const float ub = Uk_b[r * 128 + m];
  for (int tt = 0; tt < 8; ++tt) {
    const size_t hbase = ((size_t)(b * 3 + r) * 256 + tt * 32) * 128;
    __syncthreads();  // previous tile's compute done before hl overwrite
    const ushort8* hv = (const ushort8*)(h_bf + hbase);
    for (int i = tid; i < 512; i += 256) {
      ushort8 u = hv[i];
#pragma unroll
      for (int j = 0; j < 8; ++j) hl[i * 8 + j] = bf2f(u[j]);
    }
    __syncthreads();
    for (int j = 0; j < 16; ++j) {
      int tl = tr * 16 + j;
      float acc = ub;
#pragma unroll 16
      for (int n = 0; n < 128; ++n) acc += hl[tl * 128 + n] * wl[n * 128 + m];
      Uh_bf[hbase + (size_t)tl * 128 + m] = f2bf(acc * SCALE2LOG2E);
    }
  }
}

// ------ hv[b][r][t] = h[b][r][t][:].Vt_w[r];  hv2 likewise with V_w --------
__global__ __launch_bounds__(768) void k_hv(
    const unsigned short* __restrict__ h_bf, const float* __restrict__ Vt_w,
    const float* __restrict__ V_w, float* __restrict__ hv,
    float* __restrict__ hv2) {
  __shared__ float vt[384], vw[384];
  const int b = blockIdx.x, tid = threadIdx.x;
  if (tid < 384) {
    vt[tid] = Vt_w[tid];
    vw[tid] = V_w[tid];
  }
  __syncthreads();
  const int r = tid >> 8;
  const uint2* hp = (const uint2*)(h_bf + ((size_t)b * 768 + tid) * 128);
  const float* vtp = vt + r * 128;
  const float* vwp = vw + r * 128;
  float a1 = 0.f, a2 = 0.f;
#pragma unroll 8
  for (int q = 0; q < 32; ++q) {
    uint2 u = hp[q];
    int m = q * 4;
    float h0 = bf2f_lo(u.x), h1 = bf2f_hi(u.x);
    float h2 = bf2f_lo(u.y), h3 = bf2f_hi(u.y);
    a1 += vtp[m] * h0 + vtp[m + 1] * h1 + vtp[m + 2] * h2 + vtp[m + 3] * h3;
    a2 += vwp[m] * h0 + vwp[m + 1] * h1 + vwp[m + 2] * h2 + vwp[m + 3] * h3;
  }
  hv[(size_t)b * 768 + tid] = a1;
  hv2[(size_t)b * 768 + tid] = a2;
}

// ---------------- attentive RHN decoder: one block per batch row -----------
// EXACT round-5 structure (proven register-resident: FETCH 31 MB, 4.37 ms).
// Only the inner arithmetic is changed: Uh2/Tk2 prescaled by 2*log2(e),
// vk_pad holds -2vk, svk = vk_b + sum(vk); e-element = exp2+rcp+fma.
__global__ __launch_bounds__(1024, 4) void k_decoder(
    const float* __restrict__ y, const unsigned short* __restrict__ Uh_bf,
    const float* __restrict__ hv_g, const float* __restrict__ hv2_g,
    const float* __restrict__ Tk_w, const float* __restrict__ vk_w,
    const float* __restrict__ vk_b, const float* __restrict__ Wt_w,
    const float* __restrict__ Vt_b, const float* __restrict__ WHd,
    const float* __restrict__ WTd, const uint32* __restrict__ cellw,
    const float* __restrict__ RHb, const float* __restrict__ RTb,
    const float* __restrict__ W_w, const float* __restrict__ W_b,
    const float* __restrict__ V_b, float* __restrict__ out) {
  const int b = blockIdx.x, tid = threadIdx.x;

  __shared__ uint32 tk_lds[24576];  // 96 KiB packed prescaled bf16 n-pairs
  __shared__ __align__(8) float Ts_lds[3 * 136];  // padded 34-float windows
  __shared__ __align__(8) float vk_pad[3 * 136];  // -2*vk, same layout
  __shared__ __align__(8) float a_lds[768];
  __shared__ float hv_lds[768], hv2_lds[768];
  __shared__ __align__(8) float s_lds[128];
  __shared__ float cpart[8 * 128];
  __shared__ float bias_lds[1024];  // RHb[384] RTb[384] WHd[128] WTd[128]
  __shared__ float y_lds[256];
  __shared__ float redN[12], redD[12], redN2[12];
  __shared__ float svk_lds[3];
  __shared__ float ytil_lds;

  // ---- one-time LDS fills ----
  // Tk2: [r][m][j^(m&31)] prescaled packed pairs (XOR keeps reads bank-free)
  for (int i = tid; i < 24576; i += 1024) {
    int r = i >> 13, rem = i & 8191, j = rem >> 7, m = rem & 127;
    float g0 = Tk_w[(size_t)r * 16384 + (2 * j) * 128 + m] * SCALE2LOG2E;
    float g1 = Tk_w[(size_t)r * 16384 + (2 * j + 1) * 128 + m] * SCALE2LOG2E;
    tk_lds[r * 8192 + m * 64 + (j ^ (m & 31))] =
        (uint32)f2bf(g0) | ((uint32)f2bf(g1) << 16);
  }
  if (tid < 384) {
    int r = tid >> 7, m = tid & 127;
    vk_pad[r * 136 + (m >> 5) * 34 + (m & 31)] = -2.f * vk_w[tid];
    bias_lds[tid] = RHb[tid];
    bias_lds[384 + tid] = RTb[tid];
  }
  if (tid < 3) {
    float sv = vk_b[tid];
    for (int m = 0; m < 128; ++m) sv += vk_w[tid * 128 + m];
    svk_lds[tid] = sv;
  }
  if (tid < 128) {
    bias_lds[768 + tid] = WHd[tid];
    bias_lds[896 + tid] = WTd[tid];
    s_lds[tid] = 0.f;
  }
  if (tid < 256) y_lds[tid] = y[(b << 8) + tid];
  if (tid < 768) {
    hv_lds[tid] = hv_g[(size_t)b * 768 + tid];
    hv2_lds[tid] = hv2_g[(size_t)b * 768 + tid];
  }
  const float wt0 = Wt_w[0], vtb0 = Vt_b[0];

  // ---- persistent prescaled Uh: 3 r x 16 dwords = 48 VGPR ----
  const int t_e4 = tid >> 2, q4 = tid & 3;
  uint32 ureg[3][16];
#pragma unroll
  for (int r = 0; r < 3; ++r) {
    const uint4* up = (const uint4*)(Uh_bf +
        ((size_t)(b * 3 + r) * 256 + t_e4) * 128 + q4 * 32);
#pragma unroll
    for (int q = 0; q < 4; ++q) {
      uint4 v = up[q];
      ureg[r][4 * q + 0] = v.x;
      ureg[r][4 * q + 1] = v.y;
      ureg[r][4 * q + 2] = v.z;
      ureg[r][4 * q + 3] = v.w;
    }
  }
  uint32 zr;
  asm volatile("s_mov_b32 %0, 0" : "=s"(zr));
#pragma unroll
  for (int r = 0; r < 3; ++r)
#pragma unroll
    for (int q = 0; q < 16; ++q) ureg[r][q] ^= zr;
  __syncthreads();

  const int lane = tid & 63, wv = tid >> 6;
  // Ts-phase roles (tid < 768)
  const int r3t = (tid >> 8) & 3, m2 = (tid >> 1) & 127, p2 = tid & 1;
  // cell roles: 2 gates x 4 n2-chunks x 128 m
  const int gc = tid >> 9, ch = (tid >> 7) & 3, mc = tid & 127;
  const uint32* Wc = cellw + gc * 24576 + mc;
  const int n2base = ch * 16;

  for (int step = 0; step < 256; ++step) {
    // ---- Ts2[r][m] = s @ Tk2[r] ----
    if (tid < 768) {
      const uint32* tkp = tk_lds + r3t * 8192 + m2 * 64;
      const int swz = m2 & 31;
      const float* sp = s_lds + p2 * 64;
      const int jb = p2 * 32;
      float acc = 0.f;
#pragma unroll 8
      for (int jj = 0; jj < 32; ++jj) {
        uint32 w = tkp[(jb + jj) ^ swz];
        float2 sv = *(const float2*)(sp + 2 * jj);
        acc += sv.x * bf2f_lo(w) + sv.y * bf2f_hi(w);
      }
      float tot = acc + __shfl_xor(acc, 1);
      if (p2 == 0) Ts_lds[r3t * 136 + (m2 >> 5) * 34 + (m2 & 31)] = tot;
    }
    __syncthreads();  // (1)
    // ---- e[r][t'] = svk + sum(-2vk * rcp(exp2(Uh2+Ts2)+1))  (Uh in regs) ----
    {
      float er[3];
#pragma unroll
      for (int r = 0; r < 3; ++r) {
        const float2* ts2 = (const float2*)(Ts_lds + r * 136 + q4 * 34);
        const float2* vk2 = (const float2*)(vk_pad + r * 136 + q4 * 34);
        float acc0 = 0.f, acc1 = 0.f;
#pragma unroll
        for (int j = 0; j < 16; ++j) {
          uint32 w = ureg[r][j];
          float2 t2 = ts2[j], v2 = vk2[j];
          float z0 = exp2_fast(bf2f_lo(w) + t2.x);
          float z1 = exp2_fast(bf2f_hi(w) + t2.y);
          acc0 += v2.x * rcp_fast(z0 + 1.f);
          acc1 += v2.y * rcp_fast(z1 + 1.f);
        }
        float a = acc0 + acc1;
        a += __shfl_xor(a, 1);
        a += __shfl_xor(a, 2);
        er[r] = a;
      }
      if (q4 == 0) {
#pragma unroll
        for (int r = 0; r < 3; ++r) a_lds[r * 256 + t_e4] = er[r] + svk_lds[r];
      }
    }
    __syncthreads();  // (2)
    // ---- p = exp(e); num/den partial sums per r (no max-sub needed) ----
    {
      float pn = 0.f, pd = 0.f, pn2 = 0.f;
      if (tid < 768) {
        float p = __expf(a_lds[tid]);
        pd = p;
        pn = p * hv_lds[tid];
        if (step == 255) pn2 = p * hv2_lds[tid];
      }
#pragma unroll
      for (int off = 32; off; off >>= 1) {
        pn += __shfl_xor(pn, off);
        pd += __shfl_xor(pd, off);
      }
      if (step == 255) {
#pragma unroll
        for (int off = 32; off; off >>= 1) pn2 += __shfl_xor(pn2, off);
        if (lane == 0 && wv < 12) redN2[wv] = pn2;
      }
      if (lane == 0 && wv < 12) {
        redN[wv] = pn;
        redD[wv] = pd;
      }
    }
    __syncthreads();  // (3)
    // ---- cell: 3 micro-steps; l=0 dot overlaps ytil scalar ----
    const float2* sp2 = (const float2*)s_lds;
#pragma unroll
    for (int l = 0; l < 3; ++l) {
      {
        float acc = 0.f;
        const uint32* wp = Wc + (size_t)(l * 64 + n2base) * 128;
#pragma unroll 8
        for (int n2 = 0; n2 < 16; ++n2) {
          uint32 w = wp[(size_t)n2 * 128];
          float2 sv = sp2[n2base + n2];
          acc += sv.x * bf2f_lo(w) + sv.y * bf2f_hi(w);
        }
        cpart[(gc * 4 + ch) * 128 + mc] = acc;
        if (l == 0 && tid == 0) {
          float yt = y_lds[step] * wt0 + vtb0;
#pragma unroll
          for (int r = 0; r < 3; ++r) {
            float ns = redN[4 * r] + redN[4 * r + 1] + redN[4 * r + 2] + redN[4 * r + 3];
            float ds = redD[4 * r] + redD[4 * r + 1] + redD[4 * r + 2] + redD[4 * r + 3];
            yt += ns * rcp_fast(ds);
          }
          ytil_lds = yt;
        }
      }
      __syncthreads();  // cell A
      if (tid < 128) {
        float ha = cpart[tid] + cpart[128 + tid] + cpart[256 + tid] +
                   cpart[384 + tid] + bias_lds[l * 128 + tid];
        float ta = cpart[512 + tid] + cpart[640 + tid] + cpart[768 + tid] +
                   cpart[896 + tid] + bias_lds[384 + l * 128 + tid];
        if (l == 0) {
          float yt = ytil_lds;
          ha += yt * bias_lds[768 + tid];
          ta += yt * bias_lds[896 + tid];
        }
        float hvv = tanh_fast(ha);
        float tv = sigmoid_fast(ta);
        s_lds[tid] = hvv * tv + (1.f - tv) * s_lds[tid];
      }
      __syncthreads();  // cell B
    }
  }
  // ---- output head: out[b] = s.W_w + W_b + V_b + sum_r num2[r]/den[r] ----
  if (tid < 64) {
    float acc = s_lds[tid] * W_w[tid] + s_lds[tid + 64] * W_w[tid + 64];
#pragma unroll
    for (int off = 32; off; off >>= 1) acc += __shfl_xor(acc, off);
    if (tid == 0) {
      float o = acc + W_b[0] + V_b[0];
#pragma unroll
      for (int r = 0; r < 3; ++r) {
        float ns = redN2[4 * r] + redN2[4 * r + 1] + redN2[4 * r + 2] + redN2[4 * r + 3];
        float ds = redD[4 * r] + redD[4 * r + 1] + redD[4 * r + 2] + redD[4 * r + 3];
        o += ns * rcp_fast(ds);
      }
      out[b] = o;
    }
  }
}

extern "C" void kernel_launch(void* const* d_in, const int* in_sizes, int n_in,
                              void* d_out, int out_size, void* d_ws,
                              size_t ws_size, hipStream_t stream) {
  (void)in_sizes; (void)n_in; (void)out_size; (void)ws_size;
  const float* x    = (const float*)d_in[0];
  const float* y    = (const float*)d_in[1];
  const float* c0w  = (const float*)d_in[2];
  const float* c0b  = (const float*)d_in[3];
  const float* c1w  = (const float*)d_in[4];
  const float* c1b  = (const float*)d_in[5];
  const float* c2ew = (const float*)d_in[6];
  const float* c2eb = (const float*)d_in[7];
  const float* eWH  = (const float*)d_in[8];
  const float* eWT  = (const float*)d_in[9];
  const float* eRHw = (const float*)d_in[10];
  const float* eRHb = (const float*)d_in[11];
  const float* eRTw = (const float*)d_in[12];
  const float* eRTb = (const float*)d_in[13];
  const float* dWH  = (const float*)d_in[14];
  const float* dWT  = (const float*)d_in[15];
  const float* dRHw = (const float*)d_in[16];
  const float* dRHb = (const float*)d_in[17];
  const float* dRTw = (const float*)d_in[18];
  const float* dRTb = (const float*)d_in[19];
  const float* Tk   = (const float*)d_in[20];
  const float* Ukw  = (const float*)d_in[21];
  const float* Ukb  = (const float*)d_in[22];
  const float* vkw  = (const float*)d_in[23];
  const float* vkb  = (const float*)d_in[24];
  const float* Wtw  = (const float*)d_in[25];
  const float* Vtw  = (const float*)d_in[26];
  const float* Vtb  = (const float*)d_in[27];
  const float* Ww   = (const float*)d_in[28];
  const float* Wb   = (const float*)d_in[29];
  const float* Vw   = (const float*)d_in[30];
  const float* Vb   = (const float*)d_in[31];
  float* out = (float*)d_out;
  float* ws = (float*)d_ws;

  // Workspace layout (float units), same as round 5.
  unsigned short* h_bf  = (unsigned short*)ws;
  unsigned short* Uh_bf = (unsigned short*)(ws + 12582912);
  float* xph = ws + 12582912;
  float* xpt = ws + 20971520;
  float* c0o = ws + 29360128;
  float* hv  = ws + 29360128;   // aliases c0o (dead by k_hv time)
  float* hv2 = ws + 30146560;
  float* c1o = ws + 33554432;
  uint32* cellw = (uint32*)(ws + 37748736);

  k_prep<<<192, 256, 0, stream>>>(dRHw, dRTw, cellw);
  k_conv0<<<1024, 256, 0, stream>>>(x, c0w, c0b, c0o);
  k_conv1<<<1024, 256, 0, stream>>>(c0o, c1w, c1b, c1o);
  k_c2e_proj<<<1024, 256, 0, stream>>>(c1o, c2ew, c2eb, eWH, eWT, xph, xpt);
  k_encoder<<<256, 512, 0, stream>>>(xph, xpt, eRHw, eRHb, eRTw, eRTb, h_bf);
  k_uh<<<768, 256, 0, stream>>>(h_bf, Ukw, Ukb, Uh_bf);
  k_hv<<<256, 768, 0, stream>>>(h_bf, Vtw, Vw, hv, hv2);
  k_decoder<<<256, 1024, 0, stream>>>(y, Uh_bf, hv, hv2, Tk, vkw, vkb, Wtw,
                                      Vtb, dWH, dWT, cellw, dRHb, dRTb,
                                      Ww, Wb, Vb, out);
}